// Round 3
// baseline (230.709 us; speedup 1.0000x reference)
//
#include <hip/hip_runtime.h>

// QuantizedTopKSparsity on (8192, 4096) f32.
// Math collapse: gamma = rowmax(|x|) => |x/(gamma+eps)| < 1, so
// x_q = round(x/(gamma+eps)) in {-1,0,1}; abs_q in {0,1}; the k-th largest
// abs (thresh) is 0 or 1, and in both cases x_q * (abs_q >= thresh) == x_q.
// Output = rintf(x / (gamma + 1e-6f)) per row.  Memory-bound single pass.
//
// R1/R2 structure: ONE WAVE PER ROW. 64 lanes x 64 floats = 16 float4 loads
// in flight per wave (4x MLP vs R0), intra-wave shfl reduce only -- no
// __syncthreads, no LDS, waves fully independent. Nontemporal stores keep
// the streaming output out of L2/L3 so the (restore-warmed) input stays
// L3-resident.  R2 fix: __builtin_nontemporal_store needs a clang
// ext_vector_type, not HIP's float4 class.

#define ROW_D 4096
#define BLOCK 256
#define WAVES_PER_BLOCK (BLOCK / 64)
#define VEC_PER_LANE 16  // 4096 / 64 / 4
#define EPS_Q 1e-6f

typedef float v4f __attribute__((ext_vector_type(4)));

__global__ __launch_bounds__(BLOCK) void qtern_kernel(const float* __restrict__ x,
                                                      float* __restrict__ out) {
    const int wave = threadIdx.x >> 6;
    const int lane = threadIdx.x & 63;
    const long long row = (long long)blockIdx.x * WAVES_PER_BLOCK + wave;

    const v4f* __restrict__ xrow =
        reinterpret_cast<const v4f*>(x + row * (long long)ROW_D);
    v4f* __restrict__ orow = reinterpret_cast<v4f*>(out + row * (long long)ROW_D);

    // 16 coalesced 16B loads per lane -- all issued before the reduce,
    // maximizing loads in flight per wave.
    v4f v[VEC_PER_LANE];
#pragma unroll
    for (int i = 0; i < VEC_PER_LANE; ++i) v[i] = xrow[lane + 64 * i];

    float m = 0.0f;
#pragma unroll
    for (int i = 0; i < VEC_PER_LANE; ++i) {
        m = fmaxf(m, fmaxf(fmaxf(fabsf(v[i].x), fabsf(v[i].y)),
                           fmaxf(fabsf(v[i].z), fabsf(v[i].w))));
    }

    // Wave-64 butterfly max reduce -- no LDS, no barrier.
#pragma unroll
    for (int off = 32; off > 0; off >>= 1)
        m = fmaxf(m, __shfl_xor(m, off));

    const float denom = m + EPS_Q;

    // rintf = round-half-even (matches np.round); true IEEE '/' so boundary
    // cases match the numpy reference exactly. Nontemporal streaming stores.
#pragma unroll
    for (int i = 0; i < VEC_PER_LANE; ++i) {
        v4f o;
        o.x = rintf(v[i].x / denom);
        o.y = rintf(v[i].y / denom);
        o.z = rintf(v[i].z / denom);
        o.w = rintf(v[i].w / denom);
        __builtin_nontemporal_store(o, &orow[lane + 64 * i]);
    }
}

extern "C" void kernel_launch(void* const* d_in, const int* in_sizes, int n_in,
                              void* d_out, int out_size, void* d_ws, size_t ws_size,
                              hipStream_t stream) {
    const float* x = (const float*)d_in[0];
    float* out = (float*)d_out;
    const int rows = in_sizes[0] / ROW_D;                 // 8192
    const int grid = rows / WAVES_PER_BLOCK;              // 2048 blocks
    qtern_kernel<<<grid, BLOCK, 0, stream>>>(x, out);
}